// Round 12
// baseline (11584.194 us; speedup 1.0000x reference)
//
#include <hip/hip_runtime.h>
#include <hip/hip_bf16.h>
#include <cstdio>

// ---------- types / helpers ----------
typedef __attribute__((ext_vector_type(4))) float f32x4;
typedef __attribute__((ext_vector_type(8))) short bf16x8;  // 8 bf16 raw

__device__ __forceinline__ short f2b(float f) {
  unsigned u = __builtin_bit_cast(unsigned, f);
  unsigned r = (u + 0x7FFFu + ((u >> 16) & 1u)) >> 16;  // RNE
  return (short)r;
}
__device__ __forceinline__ float b2f(short s) {
  union { unsigned u; float f; } c;
  c.u = ((unsigned)(unsigned short)s) << 16;
  return c.f;
}
__device__ __forceinline__ float sigm(float x) { return 1.f / (1.f + __expf(-x)); }
__device__ __forceinline__ float tanh_f(float x) {
  float e = __expf(2.f * x);
  return 1.f - 2.f / (e + 1.f);
}

#define GLOAD16(gp, lp) \
  __builtin_amdgcn_global_load_lds((__attribute__((address_space(1))) const void*)(gp), \
                                   (__attribute__((address_space(3))) void*)(lp), 16, 0, 0)

// Problem dims: B=8 T=64 F=8 N=4096 H=32 G=32 K1=K2=3 R1=64 R2=8

// ---------- fp32 -> bf16 convert ----------
__global__ void conv_k(const float* __restrict__ in, short* __restrict__ out, int n8) {
  int i = blockIdx.x * 256 + threadIdx.x;
  if (i >= n8) return;
  size_t base = (size_t)i * 8;
  f32x4 a = *(const f32x4*)(in + base), b = *(const f32x4*)(in + base + 4);
  bf16x8 v;
#pragma unroll
  for (int j = 0; j < 4; ++j) { v[j] = f2b(a[j]); v[4 + j] = f2b(b[j]); }
  *(bf16x8*)(out + base) = v;
}

// ---------- transpose+convert (fp32 4096x4096 -> bf16) ----------
__global__ void transpose_k(const float* __restrict__ in, short* __restrict__ out) {
  __shared__ float tile[32][33];
  int bx = blockIdx.x * 32, by = blockIdx.y * 32;
  int tx = threadIdx.x, ty = threadIdx.y;
  for (int i = ty; i < 32; i += 8)
    tile[i][tx] = in[(size_t)(by + i) * 4096 + bx + tx];
  __syncthreads();
  for (int i = ty; i < 32; i += 8)
    out[(size_t)(bx + i) * 4096 + by + tx] = f2b(tile[tx][i]);
}

// ---------- preamble GEMM (pipelined, swizzled): C[M][N] = A[M][K]*Bt[N][K]^T ----------
template <int AF32>
__global__ __launch_bounds__(256) void gemm_big(const void* __restrict__ Av,
                                                const short* __restrict__ Bt,
                                                short* __restrict__ C,
                                                int K, int ldc) {
  __shared__ __align__(16) short Ab[2][128 * 64];
  __shared__ __align__(16) short Bb[2][128 * 64];
  const int tid = threadIdx.x, lane = tid & 63, w = tid >> 6;
  const int wm = w >> 1, wn = w & 1;
  const int r16 = lane & 15, g4 = lane >> 4;
  const size_t m0 = (size_t)blockIdx.y * 128, n0 = (size_t)blockIdx.x * 128;
  const int lrow8 = lane >> 3;
  const int lslot = (lane & 7) ^ lrow8;
  const int swz = r16 & 7;
  const int arow = tid >> 1, acol0 = (tid & 1) * 32, aslotb = (tid & 1) * 4;

  f32x4 acc[4][4];
#pragma unroll
  for (int mi = 0; mi < 4; ++mi)
#pragma unroll
    for (int ni = 0; ni < 4; ++ni) acc[mi][ni] = (f32x4)0.f;

  auto stageB = [&](int bs, int kt) {
#pragma unroll
    for (int i = 0; i < 4; ++i) {
      int chunk = w * 4 + i, row = chunk * 8 + lrow8;
      GLOAD16(&Bt[(size_t)(n0 + row) * K + kt + lslot * 8], &Bb[bs][chunk * 512]);
    }
  };
  auto stageA16 = [&](int bs, int kt) {
    const short* A = (const short*)Av;
#pragma unroll
    for (int i = 0; i < 4; ++i) {
      int chunk = w * 4 + i, row = chunk * 8 + lrow8;
      GLOAD16(&A[(size_t)(m0 + row) * K + kt + lslot * 8], &Ab[bs][chunk * 512]);
    }
  };
  auto writeA32 = [&](int bs, const f32x4* st) {
#pragma unroll
    for (int s = 0; s < 4; ++s) {
      bf16x8 v;
#pragma unroll
      for (int e = 0; e < 4; ++e) { v[e] = f2b(st[s * 2][e]); v[4 + e] = f2b(st[s * 2 + 1][e]); }
      int ps = (aslotb + s) ^ (arow & 7);
      *(bf16x8*)&Ab[bs][arow * 64 + ps * 8] = v;
    }
  };

  const float* A32 = (const float*)Av;
  if (AF32) {
    f32x4 st[8];
#pragma unroll
    for (int j = 0; j < 8; ++j)
      st[j] = *(const f32x4*)&A32[(m0 + arow) * (size_t)K + acol0 + j * 4];
    stageB(0, 0);
    writeA32(0, st);
  } else {
    stageA16(0, 0);
    stageB(0, 0);
  }
  __syncthreads();

  int cur = 0;
  for (int kt = 0; kt < K; kt += 64) {
    const bool nxt = (kt + 64 < K);
    f32x4 st[8];
    if (nxt) {
      if (AF32) {
#pragma unroll
        for (int j = 0; j < 8; ++j)
          st[j] = *(const f32x4*)&A32[(m0 + arow) * (size_t)K + kt + 64 + acol0 + j * 4];
      } else {
        stageA16(cur ^ 1, kt + 64);
      }
      stageB(cur ^ 1, kt + 64);
    }
#pragma unroll
    for (int ks = 0; ks < 2; ++ks) {
      const int so = ((ks * 4 + g4) ^ swz) * 8;
      bf16x8 af[4], bf[4];
#pragma unroll
      for (int i = 0; i < 4; ++i) {
        af[i] = *(const bf16x8*)&Ab[cur][(wm * 64 + i * 16 + r16) * 64 + so];
        bf[i] = *(const bf16x8*)&Bb[cur][(wn * 64 + i * 16 + r16) * 64 + so];
      }
#pragma unroll
      for (int mi = 0; mi < 4; ++mi)
#pragma unroll
        for (int ni = 0; ni < 4; ++ni)
          acc[mi][ni] = __builtin_amdgcn_mfma_f32_16x16x32_bf16(af[mi], bf[ni], acc[mi][ni], 0, 0, 0);
    }
    if (nxt && AF32) writeA32(cur ^ 1, st);
    __syncthreads();
    cur ^= 1;
  }
#pragma unroll
  for (int mi = 0; mi < 4; ++mi) {
#pragma unroll
    for (int ni = 0; ni < 4; ++ni) {
      size_t row0 = m0 + wm * 64 + mi * 16 + g4 * 4;
      size_t col  = n0 + wn * 64 + ni * 16 + r16;
#pragma unroll
      for (int r = 0; r < 4; ++r)
        C[(row0 + r) * (size_t)ldc + col] = f2b(acc[mi][ni][r]);
    }
  }
}

// ---------- grid barrier (generation counting, 256 blocks) — r8-proven ----------
__device__ __forceinline__ void gridbar(unsigned* cnt, unsigned* gen) {
  __syncthreads();
  if (threadIdx.x == 0) {
    unsigned g = __hip_atomic_load(gen, __ATOMIC_RELAXED, __HIP_MEMORY_SCOPE_AGENT);
    __threadfence();
    if (__hip_atomic_fetch_add(cnt, 1u, __ATOMIC_ACQ_REL, __HIP_MEMORY_SCOPE_AGENT) == 255u) {
      __hip_atomic_store(cnt, 0u, __ATOMIC_RELAXED, __HIP_MEMORY_SCOPE_AGENT);
      __hip_atomic_fetch_add(gen, 1u, __ATOMIC_RELEASE, __HIP_MEMORY_SCOPE_AGENT);
    } else {
      while (__hip_atomic_load(gen, __ATOMIC_ACQUIRE, __HIP_MEMORY_SCOPE_AGENT) == g)
        __builtin_amdgcn_s_sleep(8);
    }
    __threadfence();
  }
  __syncthreads();
}

// ---------- persistent recurrence: 256 blocks x 512 thr, 1 block/CU (118.6KB LDS) ----------
// Block (mhalf, ntile): rows m0..m0+127 (4 batches), node cols n0..n0+31, both taps local.
// Per step: pipelined GEMM (r9 engine) -> C,z -> LDS -> out(tau=t-1) -> gate
//           -> gridbar (gacc) -> in-register update -> gridbar.
__global__ __launch_bounds__(512, 1) void rnn_persist2(
    short* __restrict__ zbuf, const short* __restrict__ Scat,
    const float* __restrict__ x, const short* __restrict__ xsh,
    const float* __restrict__ Ca, const float* __restrict__ Cb, const float* __restrict__ bc,
    const float* __restrict__ Da, const float* __restrict__ Db, const float* __restrict__ bd,
    const float* __restrict__ Af, const float* __restrict__ Bw, const float* __restrict__ bz,
    const float* __restrict__ Wout, const float* __restrict__ bout,
    const float* __restrict__ W1, const float* __restrict__ b1,
    const float* __restrict__ W2, const float* __restrict__ b2,
    float* __restrict__ out, float* __restrict__ gacc, unsigned* __restrict__ bar) {
  __shared__ __align__(16) char smem[118624];
  short* AbB = (short*)smem;                      // Ab[2][128*64] = 32768 B
  short* BbB = (short*)(smem + 32768);            // Bb[2][64*64]  = 16384 B
  short* Cs  = (short*)smem;                      // overlay: [128][72] bf16 (18432 B)
  short* zs  = (short*)(smem + 18432);            // overlay: [128][40] bf16 (10240 B)
  float* Fu  = (float*)(smem + 49152);            // [120][32]
  float* Fd  = (float*)(smem + 64512);
  float* Fb  = (float*)(smem + 79872);            // [96][32]
  float* Fa  = (float*)(smem + 92160);            // [24][32]
  float* Wc  = (float*)(smem + 95232);            // [96][32]
  float* W1L = (float*)(smem + 107520);           // [64][32]
  float* W2L = (float*)(smem + 115712);           // [64][8]
  float* bcs   = (float*)(smem + 117760);
  float* bds   = (float*)(smem + 117888);
  float* bzL   = (float*)(smem + 118016);
  float* boutL = (float*)(smem + 118144);
  float* b1L   = (float*)(smem + 118272);         // [64]
  float* b2L   = (float*)(smem + 118528);         // [8]
  float* red   = (float*)(smem + 118560);         // [16]

  const int tid = threadIdx.x, lane = tid & 63, w = tid >> 6;
  const int wm = w >> 1, wn = w & 1;              // 4 m-strips x 2 n-strips
  const int r16 = lane & 15, g4 = lane >> 4;
  const int lrow8 = lane >> 3;
  const int lslot = (lane & 7) ^ lrow8;
  const int swz = r16 & 7;
  const int mhalf = blockIdx.x >> 7, ntile = blockIdx.x & 127;
  const int m0 = mhalf << 7, n0 = ntile << 5;

  // ---- filters -> LDS once (fp32) ----
  for (int i = tid; i < 3840; i += 512) {
    int j = i >> 5, h = i & 31; float fu, fd;
    if (j < 96) { int k = j >> 5, hh = j & 31;
      fu = Cb[(h * 3 + k) * 32 + hh]; fd = Db[(h * 3 + k) * 32 + hh]; }
    else { int jj = j - 96, k = jj >> 3, f = jj & 7;
      fu = Ca[(h * 3 + k) * 8 + f];  fd = Da[(h * 3 + k) * 8 + f]; }
    Fu[i] = fu; Fd[i] = fd;
  }
  for (int i = tid; i < 3072; i += 512) { int j = i >> 5, h = i & 31, k = j >> 5, hh = j & 31;
    Fb[i] = Bw[(h * 3 + k) * 32 + hh]; }
  for (int i = tid; i < 768;  i += 512) { int j = i >> 5, h = i & 31, k = j >> 3, f = j & 7;
    Fa[i] = Af[(h * 3 + k) * 8 + f]; }
  for (int i = tid; i < 3072; i += 512) { int j = i >> 5, g = i & 31, k = j >> 5, hh = j & 31;
    Wc[i] = Wout[(g * 3 + k) * 32 + hh]; }
  for (int i = tid; i < 2048; i += 512) { int r1 = i >> 5, g = i & 31; W1L[i] = W1[r1 * 32 + g]; }
  if (tid < 512) { int r1 = tid >> 3, r = tid & 7; W2L[tid] = W2[r * 64 + r1]; }
  if (tid < 32) { bcs[tid] = bc[tid]; bds[tid] = bd[tid]; bzL[tid] = bz[tid]; boutL[tid] = bout[tid]; }
  if (tid < 64) b1L[tid] = b1[tid];
  if (tid < 8)  b2L[tid] = b2[tid];
  __syncthreads();

  for (int t = 0; t <= 64; ++t) {
    const short* z = zbuf + (size_t)(t & 1) * 1048576;

    // ---- pipelined GEMM: C[128][64] = z[m0..+128] x [tap1;tap2] rows of this n-tile ----
    f32x4 acc[2][2];
    acc[0][0] = acc[0][1] = acc[1][0] = acc[1][1] = (f32x4)0.f;
    auto stage = [&](int bs, int kt) {
#pragma unroll
      for (int i = 0; i < 2; ++i) {              // A: 16 chunks of 8 rows
        int chunk = w * 2 + i, row = chunk * 8 + lrow8;
        GLOAD16(&z[(size_t)(m0 + row) * 4096 + kt + lslot * 8], &AbB[bs * 8192 + chunk * 512]);
      }
      {                                          // B: 8 chunks; rows 0..31 tap1, 32..63 tap2
        int row = w * 8 + lrow8;
        int grow = (row < 32) ? (n0 + row) : (4064 + n0 + row);
        GLOAD16(&Scat[(size_t)grow * 4096 + kt + lslot * 8], &BbB[bs * 4096 + w * 512]);
      }
    };
    stage(0, 0);
    __syncthreads();
    int cur = 0;
    for (int kt = 0; kt < 4096; kt += 64) {
      if (kt + 64 < 4096) stage(cur ^ 1, kt + 64);
#pragma unroll
      for (int ks = 0; ks < 2; ++ks) {
        const int so = ((ks * 4 + g4) ^ swz) * 8;
        bf16x8 af[2], bb[2];
#pragma unroll
        for (int i = 0; i < 2; ++i) {
          af[i] = *(const bf16x8*)&AbB[cur * 8192 + (wm * 32 + i * 16 + r16) * 64 + so];
          bb[i] = *(const bf16x8*)&BbB[cur * 4096 + (wn * 32 + i * 16 + r16) * 64 + so];
        }
#pragma unroll
        for (int mi = 0; mi < 2; ++mi)
#pragma unroll
          for (int ni = 0; ni < 2; ++ni)
            acc[mi][ni] = __builtin_amdgcn_mfma_f32_16x16x32_bf16(af[mi], bb[ni], acc[mi][ni], 0, 0, 0);
      }
      __syncthreads();
      cur ^= 1;
    }
    // ---- C -> Cs (stride 72), z-tile -> zs (stride 40) ----
#pragma unroll
    for (int mi = 0; mi < 2; ++mi)
#pragma unroll
      for (int ni = 0; ni < 2; ++ni) {
        int row0 = wm * 32 + mi * 16 + g4 * 4, col = wn * 32 + ni * 16 + r16;
#pragma unroll
        for (int rr = 0; rr < 4; ++rr)
          Cs[(row0 + rr) * 72 + col] = f2b(acc[mi][ni][rr]);
      }
    { int row = tid >> 2, c0 = (tid & 3) * 8;
      *(bf16x8*)&zs[row * 40 + c0] = *(const bf16x8*)&z[(size_t)(m0 + row) * 4096 + n0 + c0]; }
    __syncthreads();

    // ---- OUT phase (tau = t-1), threads 0..127 ----
    if (t >= 1 && tid < 128) {
      int b_loc = tid >> 5, nn = tid & 31;
      int b_glob = (mhalf << 2) + b_loc;
      f32x4 oa[8];
#pragma unroll
      for (int q = 0; q < 8; ++q) oa[q] = (f32x4)0.f;
      for (int j = 0; j < 96; ++j) {
        int k = j >> 5, hh = j & 31;
        float v = (k == 0) ? b2f(zs[(b_loc * 32 + hh) * 40 + nn])
                           : b2f(Cs[(b_loc * 32 + hh) * 72 + (k - 1) * 32 + nn]);
#pragma unroll
        for (int q = 0; q < 8; ++q) oa[q] += (*(const f32x4*)&Wc[j * 32 + q * 4]) * v;
      }
      f32x4 y[8];
#pragma unroll
      for (int q = 0; q < 8; ++q)
#pragma unroll
        for (int c = 0; c < 4; ++c) y[q][c] = tanh_f(oa[q][c] + boutL[q * 4 + c]);
      f32x4 o0 = { b2L[0], b2L[1], b2L[2], b2L[3] };
      f32x4 o1 = { b2L[4], b2L[5], b2L[6], b2L[7] };
      for (int r1 = 0; r1 < 64; ++r1) {
        f32x4 p = y[0] * (*(const f32x4*)&W1L[r1 * 32]);
#pragma unroll
        for (int q = 1; q < 8; ++q) p += y[q] * (*(const f32x4*)&W1L[r1 * 32 + q * 4]);
        float hv = b1L[r1] + p[0] + p[1] + p[2] + p[3];
        hv = fmaxf(hv, 0.f);
        o0 += (*(const f32x4*)&W2L[r1 * 8]) * hv;
        o1 += (*(const f32x4*)&W2L[r1 * 8 + 4]) * hv;
      }
      size_t obase = ((size_t)(b_glob * 64 + (t - 1)) * 8) * 4096 + n0 + nn;
#pragma unroll
      for (int rr = 0; rr < 4; ++rr) {
        out[obase + (size_t)rr * 4096]       = o0[rr];
        out[obase + (size_t)(4 + rr) * 4096] = o1[rr];
      }
    }

    // ---- GATE phase (za/zb live in registers through the barrier) ----
    f32x4 zaA = (f32x4)0.f, zaB = (f32x4)0.f, zbA = (f32x4)0.f, zbB = (f32x4)0.f;
    int b_glob = 0, b_loc = 0, h0 = 0, nn = 0;
    if (t < 64) {
      nn = tid & 31; int q = tid >> 5; b_loc = q >> 2; h0 = (q & 3) * 8;
      b_glob = (mhalf << 2) + b_loc;
      f32x4 guA = *(const f32x4*)&bcs[h0], guB = *(const f32x4*)&bcs[h0 + 4];
      f32x4 gdA = *(const f32x4*)&bds[h0], gdB = *(const f32x4*)&bds[h0 + 4];
      for (int j = 0; j < 96; ++j) {
        int k = j >> 5, hh = j & 31;
        float v = (k == 0) ? b2f(zs[(b_loc * 32 + hh) * 40 + nn])
                           : b2f(Cs[(b_loc * 32 + hh) * 72 + (k - 1) * 32 + nn]);
        guA += (*(const f32x4*)&Fu[j * 32 + h0]) * v;  guB += (*(const f32x4*)&Fu[j * 32 + h0 + 4]) * v;
        gdA += (*(const f32x4*)&Fd[j * 32 + h0]) * v;  gdB += (*(const f32x4*)&Fd[j * 32 + h0 + 4]) * v;
        zbA += (*(const f32x4*)&Fb[j * 32 + h0]) * v;  zbB += (*(const f32x4*)&Fb[j * 32 + h0 + 4]) * v;
      }
      size_t xr = ((size_t)b_glob * 64 + t) * 8;
      for (int j = 0; j < 24; ++j) {
        int k = j >> 3, f = j & 7;
        float v = (k == 0) ? x[(xr + f) * 4096 + n0 + nn]
                           : b2f(xsh[(xr + f) * 8192 + (size_t)(k - 1) * 4096 + n0 + nn]);
        guA += (*(const f32x4*)&Fu[(96 + j) * 32 + h0]) * v;  guB += (*(const f32x4*)&Fu[(96 + j) * 32 + h0 + 4]) * v;
        gdA += (*(const f32x4*)&Fd[(96 + j) * 32 + h0]) * v;  gdB += (*(const f32x4*)&Fd[(96 + j) * 32 + h0 + 4]) * v;
        zaA += (*(const f32x4*)&Fa[j * 32 + h0]) * v;         zaB += (*(const f32x4*)&Fa[j * 32 + h0 + 4]) * v;
      }
      float su = 0.f, sd = 0.f;
#pragma unroll
      for (int i = 0; i < 4; ++i) {
        su += sigm(guA[i]) + sigm(guB[i]);
        sd += sigm(gdA[i]) + sigm(gdB[i]);
      }
#pragma unroll
      for (int off = 32; off; off >>= 1) { su += __shfl_down(su, off); sd += __shfl_down(sd, off); }
      if (lane == 0) { red[w * 2] = su; red[w * 2 + 1] = sd; }
      __syncthreads();
      if (tid < 4) {     // batch tid: waves 2*tid, 2*tid+1
        int par = t & 1, bg = (mhalf << 2) + tid;
        atomicAdd(&gacc[par * 16 + bg],     red[4 * tid] + red[4 * tid + 2]);
        atomicAdd(&gacc[par * 16 + 8 + bg], red[4 * tid + 1] + red[4 * tid + 3]);
      }
    }
    if (t < 64) {
      gridbar(bar, bar + 1);     // gacc complete
      const int par = t & 1;
      float u  = gacc[par * 16 + b_glob]     * (1.f / 131072.f);
      float fg = gacc[par * 16 + 8 + b_glob] * (1.f / 131072.f);
      short* znxt = zbuf + (size_t)((t + 1) & 1) * 1048576;
#pragma unroll
      for (int i = 0; i < 4; ++i) {
        znxt[(size_t)(m0 + b_loc * 32 + h0 + i) * 4096 + n0 + nn]
            = f2b(tanh_f(u * zaA[i] + fg * zbA[i] + bzL[h0 + i]));
        znxt[(size_t)(m0 + b_loc * 32 + h0 + 4 + i) * 4096 + n0 + nn]
            = f2b(tanh_f(u * zaB[i] + fg * zbB[i] + bzL[h0 + 4 + i]));
      }
      if (blockIdx.x == 0 && tid < 16) gacc[((par ^ 1) * 16) + tid] = 0.f;
      gridbar(bar, bar + 1);     // z_{t+1} complete
    }
  }
}

// ---------- host ----------
extern "C" void kernel_launch(void* const* d_in, const int* in_sizes, int n_in,
                              void* d_out, int out_size, void* d_ws, size_t ws_size,
                              hipStream_t stream) {
  const float* x    = (const float*)d_in[0];
  const float* z0   = (const float*)d_in[1];
  const float* S    = (const float*)d_in[2];
  const float* Af   = (const float*)d_in[3];
  const float* Bw   = (const float*)d_in[4];
  const float* bz   = (const float*)d_in[5];
  const float* Ca   = (const float*)d_in[6];
  const float* Cb   = (const float*)d_in[7];
  const float* bc   = (const float*)d_in[8];
  const float* Da   = (const float*)d_in[9];
  const float* Db   = (const float*)d_in[10];
  const float* bd   = (const float*)d_in[11];
  const float* Wout = (const float*)d_in[12];
  const float* bo   = (const float*)d_in[13];
  const float* W1   = (const float*)d_in[14];
  const float* b1   = (const float*)d_in[15];
  const float* W2   = (const float*)d_in[16];
  const float* b2   = (const float*)d_in[17];
  float* out = (float*)d_out;

  // workspace layout (~138.6 MiB)
  char* w = (char*)d_ws;
  short* Scat = (short*)w; w += (size_t)8192 * 4096 * 2;   // bf16 [S ; S^2]          67.1 MB
  short* xsh  = (short*)w; w += (size_t)4096 * 8192 * 2;   // bf16 x shifts (tmp S^T) 67.1 MB
  short* zbuf = (short*)w; w += (size_t)2 * 1048576 * 2;   // bf16 z ping-pong         4.2 MB
  float* gacc = (float*)w; w += 256;                       // 2x16 gacc + bar cnt/gen
  unsigned* bar = (unsigned*)(gacc + 32);
  size_t need = (size_t)(w - (char*)d_ws);
  if (ws_size < need) {
    fprintf(stderr, "kernel_launch: WS TOO SMALL need=%zu have=%zu -- NOT LAUNCHING\n",
            need, ws_size);
    return;
  }

  short* STt = xsh;  // temp: bf16 S^T (consumed by S^2 GEMM before xsh is written)

  conv_k<<<512, 256, 0, stream>>>(z0, zbuf, 131072);            // bf16 z_0
  conv_k<<<8192, 256, 0, stream>>>(S, Scat, 2097152);           // bf16 S
  transpose_k<<<dim3(128, 128), dim3(32, 8), 0, stream>>>(S, STt);
  gemm_big<0><<<dim3(32, 32), 256, 0, stream>>>(Scat, STt, Scat + (size_t)4096 * 4096, 4096, 4096);
  gemm_big<1><<<dim3(64, 32), 256, 0, stream>>>(x, Scat, xsh, 4096, 8192);
  hipMemsetAsync(gacc, 0, 256, stream);

  rnn_persist2<<<256, 512, 0, stream>>>(zbuf, Scat, x, xsh,
                                        Ca, Cb, bc, Da, Db, bd, Af, Bw, bz,
                                        Wout, bo, W1, b1, W2, b2,
                                        out, gacc, bar);
}

// Round 13
// 6905.195 us; speedup vs baseline: 1.6776x; 1.6776x over previous
//
#include <hip/hip_runtime.h>
#include <hip/hip_bf16.h>
#include <cstdio>

// ---------- types / helpers ----------
typedef __attribute__((ext_vector_type(4))) float f32x4;
typedef __attribute__((ext_vector_type(8))) short bf16x8;  // 8 bf16 raw

__device__ __forceinline__ short f2b(float f) {
  unsigned u = __builtin_bit_cast(unsigned, f);
  unsigned r = (u + 0x7FFFu + ((u >> 16) & 1u)) >> 16;  // RNE
  return (short)r;
}
__device__ __forceinline__ float b2f(short s) {
  union { unsigned u; float f; } c;
  c.u = ((unsigned)(unsigned short)s) << 16;
  return c.f;
}
__device__ __forceinline__ float sigm(float x) { return 1.f / (1.f + __expf(-x)); }
__device__ __forceinline__ float tanh_f(float x) {
  float e = __expf(2.f * x);
  return 1.f - 2.f / (e + 1.f);
}

#define GLOAD16(gp, lp) \
  __builtin_amdgcn_global_load_lds((__attribute__((address_space(1))) const void*)(gp), \
                                   (__attribute__((address_space(3))) void*)(lp), 16, 0, 0)

// Problem dims: B=8 T=64 F=8 N=4096 H=32 G=32 K1=K2=3 R1=64 R2=8

// ---------- fp32 -> bf16 convert ----------
__global__ void conv_k(const float* __restrict__ in, short* __restrict__ out, int n8) {
  int i = blockIdx.x * 256 + threadIdx.x;
  if (i >= n8) return;
  size_t base = (size_t)i * 8;
  f32x4 a = *(const f32x4*)(in + base), b = *(const f32x4*)(in + base + 4);
  bf16x8 v;
#pragma unroll
  for (int j = 0; j < 4; ++j) { v[j] = f2b(a[j]); v[4 + j] = f2b(b[j]); }
  *(bf16x8*)(out + base) = v;
}

// ---------- transpose+convert (fp32 4096x4096 -> bf16) ----------
__global__ void transpose_k(const float* __restrict__ in, short* __restrict__ out) {
  __shared__ float tile[32][33];
  int bx = blockIdx.x * 32, by = blockIdx.y * 32;
  int tx = threadIdx.x, ty = threadIdx.y;
  for (int i = ty; i < 32; i += 8)
    tile[i][tx] = in[(size_t)(by + i) * 4096 + bx + tx];
  __syncthreads();
  for (int i = ty; i < 32; i += 8)
    out[(size_t)(bx + i) * 4096 + by + tx] = f2b(tile[tx][i]);
}

// ---------- preamble GEMM (pipelined, swizzled) — execution-proven in r12 ----------
template <int AF32>
__global__ __launch_bounds__(256) void gemm_big(const void* __restrict__ Av,
                                                const short* __restrict__ Bt,
                                                short* __restrict__ C,
                                                int K, int ldc) {
  __shared__ __align__(16) short Ab[2][128 * 64];
  __shared__ __align__(16) short Bb[2][128 * 64];
  const int tid = threadIdx.x, lane = tid & 63, w = tid >> 6;
  const int wm = w >> 1, wn = w & 1;
  const int r16 = lane & 15, g4 = lane >> 4;
  const size_t m0 = (size_t)blockIdx.y * 128, n0 = (size_t)blockIdx.x * 128;
  const int lrow8 = lane >> 3;
  const int lslot = (lane & 7) ^ lrow8;
  const int swz = r16 & 7;
  const int arow = tid >> 1, acol0 = (tid & 1) * 32, aslotb = (tid & 1) * 4;

  f32x4 acc[4][4];
#pragma unroll
  for (int mi = 0; mi < 4; ++mi)
#pragma unroll
    for (int ni = 0; ni < 4; ++ni) acc[mi][ni] = (f32x4)0.f;

  auto stageB = [&](int bs, int kt) {
#pragma unroll
    for (int i = 0; i < 4; ++i) {
      int chunk = w * 4 + i, row = chunk * 8 + lrow8;
      GLOAD16(&Bt[(size_t)(n0 + row) * K + kt + lslot * 8], &Bb[bs][chunk * 512]);
    }
  };
  auto stageA16 = [&](int bs, int kt) {
    const short* A = (const short*)Av;
#pragma unroll
    for (int i = 0; i < 4; ++i) {
      int chunk = w * 4 + i, row = chunk * 8 + lrow8;
      GLOAD16(&A[(size_t)(m0 + row) * K + kt + lslot * 8], &Ab[bs][chunk * 512]);
    }
  };
  auto writeA32 = [&](int bs, const f32x4* st) {
#pragma unroll
    for (int s = 0; s < 4; ++s) {
      bf16x8 v;
#pragma unroll
      for (int e = 0; e < 4; ++e) { v[e] = f2b(st[s * 2][e]); v[4 + e] = f2b(st[s * 2 + 1][e]); }
      int ps = (aslotb + s) ^ (arow & 7);
      *(bf16x8*)&Ab[bs][arow * 64 + ps * 8] = v;
    }
  };

  const float* A32 = (const float*)Av;
  if (AF32) {
    f32x4 st[8];
#pragma unroll
    for (int j = 0; j < 8; ++j)
      st[j] = *(const f32x4*)&A32[(m0 + arow) * (size_t)K + acol0 + j * 4];
    stageB(0, 0);
    writeA32(0, st);
  } else {
    stageA16(0, 0);
    stageB(0, 0);
  }
  __syncthreads();

  int cur = 0;
  for (int kt = 0; kt < K; kt += 64) {
    const bool nxt = (kt + 64 < K);
    f32x4 st[8];
    if (nxt) {
      if (AF32) {
#pragma unroll
        for (int j = 0; j < 8; ++j)
          st[j] = *(const f32x4*)&A32[(m0 + arow) * (size_t)K + kt + 64 + acol0 + j * 4];
      } else {
        stageA16(cur ^ 1, kt + 64);
      }
      stageB(cur ^ 1, kt + 64);
    }
#pragma unroll
    for (int ks = 0; ks < 2; ++ks) {
      const int so = ((ks * 4 + g4) ^ swz) * 8;
      bf16x8 af[4], bf[4];
#pragma unroll
      for (int i = 0; i < 4; ++i) {
        af[i] = *(const bf16x8*)&Ab[cur][(wm * 64 + i * 16 + r16) * 64 + so];
        bf[i] = *(const bf16x8*)&Bb[cur][(wn * 64 + i * 16 + r16) * 64 + so];
      }
#pragma unroll
      for (int mi = 0; mi < 4; ++mi)
#pragma unroll
        for (int ni = 0; ni < 4; ++ni)
          acc[mi][ni] = __builtin_amdgcn_mfma_f32_16x16x32_bf16(af[mi], bf[ni], acc[mi][ni], 0, 0, 0);
    }
    if (nxt && AF32) writeA32(cur ^ 1, st);
    __syncthreads();
    cur ^= 1;
  }
#pragma unroll
  for (int mi = 0; mi < 4; ++mi) {
#pragma unroll
    for (int ni = 0; ni < 4; ++ni) {
      size_t row0 = m0 + wm * 64 + mi * 16 + g4 * 4;
      size_t col  = n0 + wn * 64 + ni * 16 + r16;
#pragma unroll
      for (int r = 0; r < 4; ++r)
        C[(row0 + r) * (size_t)ldc + col] = f2b(acc[mi][ni][r]);
    }
  }
}

// ---------- K1: fused per-step gemm + out + gate (r12 body, NO grid barriers) ----------
// 256 blocks x 512 thr, 1 block/CU. Block (mhalf, ntile): rows m0..m0+127, cols n0..n0+31.
// GEMM taps stay in LDS; OUT(tau=t-1) + GATE consume them; gate writes za/zb to
// global + gacc atomics. Sync to the update is the kernel boundary.
__global__ __launch_bounds__(512, 1) void step_fused(
    const short* __restrict__ zbuf, const short* __restrict__ Scat,
    const float* __restrict__ x, const short* __restrict__ xsh,
    const float* __restrict__ Ca, const float* __restrict__ Cb, const float* __restrict__ bc,
    const float* __restrict__ Da, const float* __restrict__ Db, const float* __restrict__ bd,
    const float* __restrict__ Af, const float* __restrict__ Bw,
    const float* __restrict__ Wout, const float* __restrict__ bout,
    const float* __restrict__ W1, const float* __restrict__ b1,
    const float* __restrict__ W2, const float* __restrict__ b2,
    float* __restrict__ zab, float* __restrict__ gacc,
    float* __restrict__ out, int t) {
  __shared__ __align__(16) char smem[118624];
  short* AbB = (short*)smem;                      // Ab[2][128*64] = 32768 B
  short* BbB = (short*)(smem + 32768);            // Bb[2][64*64]  = 16384 B
  short* Cs  = (short*)smem;                      // overlay: [128][72] bf16
  short* zs  = (short*)(smem + 18432);            // overlay: [128][40] bf16
  float* Fu  = (float*)(smem + 49152);            // [120][32]
  float* Fd  = (float*)(smem + 64512);
  float* Fb  = (float*)(smem + 79872);            // [96][32]
  float* Fa  = (float*)(smem + 92160);            // [24][32]
  float* Wc  = (float*)(smem + 95232);            // [96][32]
  float* W1L = (float*)(smem + 107520);           // [64][32]
  float* W2L = (float*)(smem + 115712);           // [64][8]
  float* bcs   = (float*)(smem + 117760);
  float* bds   = (float*)(smem + 117888);
  float* boutL = (float*)(smem + 118144);
  float* b1L   = (float*)(smem + 118272);         // [64]
  float* b2L   = (float*)(smem + 118528);         // [8]
  float* red   = (float*)(smem + 118560);         // [16]

  const int tid = threadIdx.x, lane = tid & 63, w = tid >> 6;
  const int wm = w >> 1, wn = w & 1;              // 4 m-strips x 2 n-strips
  const int r16 = lane & 15, g4 = lane >> 4;
  const int lrow8 = lane >> 3;
  const int lslot = (lane & 7) ^ lrow8;
  const int swz = r16 & 7;
  const int mhalf = blockIdx.x >> 7, ntile = blockIdx.x & 127;
  const int m0 = mhalf << 7, n0 = ntile << 5;

  // ---- filters -> LDS (fp32) ----
  for (int i = tid; i < 3840; i += 512) {
    int j = i >> 5, h = i & 31; float fu, fd;
    if (j < 96) { int k = j >> 5, hh = j & 31;
      fu = Cb[(h * 3 + k) * 32 + hh]; fd = Db[(h * 3 + k) * 32 + hh]; }
    else { int jj = j - 96, k = jj >> 3, f = jj & 7;
      fu = Ca[(h * 3 + k) * 8 + f];  fd = Da[(h * 3 + k) * 8 + f]; }
    Fu[i] = fu; Fd[i] = fd;
  }
  for (int i = tid; i < 3072; i += 512) { int j = i >> 5, h = i & 31, k = j >> 5, hh = j & 31;
    Fb[i] = Bw[(h * 3 + k) * 32 + hh]; }
  for (int i = tid; i < 768;  i += 512) { int j = i >> 5, h = i & 31, k = j >> 3, f = j & 7;
    Fa[i] = Af[(h * 3 + k) * 8 + f]; }
  for (int i = tid; i < 3072; i += 512) { int j = i >> 5, g = i & 31, k = j >> 5, hh = j & 31;
    Wc[i] = Wout[(g * 3 + k) * 32 + hh]; }
  for (int i = tid; i < 2048; i += 512) { int r1 = i >> 5, g = i & 31; W1L[i] = W1[r1 * 32 + g]; }
  if (tid < 512) { int r1 = tid >> 3, r = tid & 7; W2L[tid] = W2[r * 64 + r1]; }
  if (tid < 32) { bcs[tid] = bc[tid]; bds[tid] = bd[tid]; boutL[tid] = bout[tid]; }
  if (tid < 64) b1L[tid] = b1[tid];
  if (tid < 8)  b2L[tid] = b2[tid];
  __syncthreads();

  const short* z = zbuf + (size_t)(t & 1) * 1048576;

  // ---- pipelined GEMM: taps C[128][64] = z[m0..+128] x [tap1;tap2] of this n-tile ----
  f32x4 acc[2][2];
  acc[0][0] = acc[0][1] = acc[1][0] = acc[1][1] = (f32x4)0.f;
  auto stage = [&](int bs, int kt) {
#pragma unroll
    for (int i = 0; i < 2; ++i) {
      int chunk = w * 2 + i, row = chunk * 8 + lrow8;
      GLOAD16(&z[(size_t)(m0 + row) * 4096 + kt + lslot * 8], &AbB[bs * 8192 + chunk * 512]);
    }
    { int row = w * 8 + lrow8;
      int grow = (row < 32) ? (n0 + row) : (4064 + n0 + row);
      GLOAD16(&Scat[(size_t)grow * 4096 + kt + lslot * 8], &BbB[bs * 4096 + w * 512]); }
  };
  stage(0, 0);
  __syncthreads();
  int cur = 0;
  for (int kt = 0; kt < 4096; kt += 64) {
    if (kt + 64 < 4096) stage(cur ^ 1, kt + 64);
#pragma unroll
    for (int ks = 0; ks < 2; ++ks) {
      const int so = ((ks * 4 + g4) ^ swz) * 8;
      bf16x8 af[2], bb[2];
#pragma unroll
      for (int i = 0; i < 2; ++i) {
        af[i] = *(const bf16x8*)&AbB[cur * 8192 + (wm * 32 + i * 16 + r16) * 64 + so];
        bb[i] = *(const bf16x8*)&BbB[cur * 4096 + (wn * 32 + i * 16 + r16) * 64 + so];
      }
#pragma unroll
      for (int mi = 0; mi < 2; ++mi)
#pragma unroll
        for (int ni = 0; ni < 2; ++ni)
          acc[mi][ni] = __builtin_amdgcn_mfma_f32_16x16x32_bf16(af[mi], bb[ni], acc[mi][ni], 0, 0, 0);
    }
    __syncthreads();
    cur ^= 1;
  }
  // ---- C -> Cs (stride 72), z-tile -> zs (stride 40) ----
#pragma unroll
  for (int mi = 0; mi < 2; ++mi)
#pragma unroll
    for (int ni = 0; ni < 2; ++ni) {
      int row0 = wm * 32 + mi * 16 + g4 * 4, col = wn * 32 + ni * 16 + r16;
#pragma unroll
      for (int rr = 0; rr < 4; ++rr)
        Cs[(row0 + rr) * 72 + col] = f2b(acc[mi][ni][rr]);
    }
  { int row = tid >> 2, c0 = (tid & 3) * 8;
    *(bf16x8*)&zs[row * 40 + c0] = *(const bf16x8*)&z[(size_t)(m0 + row) * 4096 + n0 + c0]; }
  __syncthreads();

  // ---- OUT phase (tau = t-1), threads 0..127 ----
  if (t >= 1 && tid < 128) {
    int b_loc = tid >> 5, nn = tid & 31;
    int b_glob = (mhalf << 2) + b_loc;
    f32x4 oa[8];
#pragma unroll
    for (int q = 0; q < 8; ++q) oa[q] = (f32x4)0.f;
    for (int j = 0; j < 96; ++j) {
      int k = j >> 5, hh = j & 31;
      float v = (k == 0) ? b2f(zs[(b_loc * 32 + hh) * 40 + nn])
                         : b2f(Cs[(b_loc * 32 + hh) * 72 + (k - 1) * 32 + nn]);
#pragma unroll
      for (int q = 0; q < 8; ++q) oa[q] += (*(const f32x4*)&Wc[j * 32 + q * 4]) * v;
    }
    f32x4 y[8];
#pragma unroll
    for (int q = 0; q < 8; ++q)
#pragma unroll
      for (int c = 0; c < 4; ++c) y[q][c] = tanh_f(oa[q][c] + boutL[q * 4 + c]);
    f32x4 o0 = { b2L[0], b2L[1], b2L[2], b2L[3] };
    f32x4 o1 = { b2L[4], b2L[5], b2L[6], b2L[7] };
    for (int r1 = 0; r1 < 64; ++r1) {
      f32x4 p = y[0] * (*(const f32x4*)&W1L[r1 * 32]);
#pragma unroll
      for (int q = 1; q < 8; ++q) p += y[q] * (*(const f32x4*)&W1L[r1 * 32 + q * 4]);
      float hv = b1L[r1] + p[0] + p[1] + p[2] + p[3];
      hv = fmaxf(hv, 0.f);
      o0 += (*(const f32x4*)&W2L[r1 * 8]) * hv;
      o1 += (*(const f32x4*)&W2L[r1 * 8 + 4]) * hv;
    }
    size_t obase = ((size_t)(b_glob * 64 + (t - 1)) * 8) * 4096 + n0 + nn;
#pragma unroll
    for (int rr = 0; rr < 4; ++rr) {
      out[obase + (size_t)rr * 4096]       = o0[rr];
      out[obase + (size_t)(4 + rr) * 4096] = o1[rr];
    }
  }

  // ---- GATE phase: za/zb -> global, gu/gd -> gacc atomics ----
  if (t < 64) {
    int nn = tid & 31; int q = tid >> 5; int b_loc = q >> 2; int h0 = (q & 3) * 8;
    int b_glob = (mhalf << 2) + b_loc;
    int n = n0 + nn;
    f32x4 zaA = (f32x4)0.f, zaB = (f32x4)0.f, zbA = (f32x4)0.f, zbB = (f32x4)0.f;
    f32x4 guA = *(const f32x4*)&bcs[h0], guB = *(const f32x4*)&bcs[h0 + 4];
    f32x4 gdA = *(const f32x4*)&bds[h0], gdB = *(const f32x4*)&bds[h0 + 4];
    for (int j = 0; j < 96; ++j) {
      int k = j >> 5, hh = j & 31;
      float v = (k == 0) ? b2f(zs[(b_loc * 32 + hh) * 40 + nn])
                         : b2f(Cs[(b_loc * 32 + hh) * 72 + (k - 1) * 32 + nn]);
      guA += (*(const f32x4*)&Fu[j * 32 + h0]) * v;  guB += (*(const f32x4*)&Fu[j * 32 + h0 + 4]) * v;
      gdA += (*(const f32x4*)&Fd[j * 32 + h0]) * v;  gdB += (*(const f32x4*)&Fd[j * 32 + h0 + 4]) * v;
      zbA += (*(const f32x4*)&Fb[j * 32 + h0]) * v;  zbB += (*(const f32x4*)&Fb[j * 32 + h0 + 4]) * v;
    }
    size_t xr = ((size_t)b_glob * 64 + t) * 8;
    for (int j = 0; j < 24; ++j) {
      int k = j >> 3, f = j & 7;
      float v = (k == 0) ? x[(xr + f) * 4096 + n]
                         : b2f(xsh[(xr + f) * 8192 + (size_t)(k - 1) * 4096 + n]);
      guA += (*(const f32x4*)&Fu[(96 + j) * 32 + h0]) * v;  guB += (*(const f32x4*)&Fu[(96 + j) * 32 + h0 + 4]) * v;
      gdA += (*(const f32x4*)&Fd[(96 + j) * 32 + h0]) * v;  gdB += (*(const f32x4*)&Fd[(96 + j) * 32 + h0 + 4]) * v;
      zaA += (*(const f32x4*)&Fa[j * 32 + h0]) * v;         zaB += (*(const f32x4*)&Fa[j * 32 + h0 + 4]) * v;
    }
    float su = 0.f, sd = 0.f;
    size_t zr = (size_t)(b_glob * 32 + h0) * 4096 + n;
#pragma unroll
    for (int i = 0; i < 4; ++i) {
      su += sigm(guA[i]) + sigm(guB[i]);
      sd += sigm(gdA[i]) + sigm(gdB[i]);
      zab[zr + (size_t)i * 4096]                 = zaA[i];
      zab[zr + (size_t)(4 + i) * 4096]           = zaB[i];
      zab[1048576 + zr + (size_t)i * 4096]       = zbA[i];
      zab[1048576 + zr + (size_t)(4 + i) * 4096] = zbB[i];
    }
#pragma unroll
    for (int off = 32; off; off >>= 1) { su += __shfl_down(su, off); sd += __shfl_down(sd, off); }
    if (lane == 0) { red[w * 2] = su; red[w * 2 + 1] = sd; }
    __syncthreads();
    if (tid < 4) {     // batch tid: waves 2*tid, 2*tid+1
      int par = t & 1, bg = (mhalf << 2) + tid;
      atomicAdd(&gacc[par * 16 + bg],     red[4 * tid] + red[4 * tid + 2]);
      atomicAdd(&gacc[par * 16 + 8 + bg], red[4 * tid + 1] + red[4 * tid + 3]);
    }
  }
}

// ---------- K2: per-step state update (bf16 z out) + zero next parity gacc ----------
__global__ __launch_bounds__(256) void update_kernel(
    const float* __restrict__ zab, float* __restrict__ gacc,
    const float* __restrict__ bz, short* __restrict__ zout, int t) {
  const int par = t & 1;
  if (blockIdx.x == 0 && threadIdx.x < 16) gacc[(par ^ 1) * 16 + threadIdx.x] = 0.f;
  size_t idx = (size_t)blockIdx.x * 256 + threadIdx.x;   // 131072 threads
  size_t base = idx * 8;
  int row = (int)(base >> 12);
  int b = row >> 5, h = row & 31;
  float u  = gacc[par * 16 + b]     * (1.f / 131072.f);
  float fg = gacc[par * 16 + 8 + b] * (1.f / 131072.f);
  float bzv = bz[h];
  f32x4 za0 = *(const f32x4*)(zab + base),           za1 = *(const f32x4*)(zab + base + 4);
  f32x4 zb0 = *(const f32x4*)(zab + 1048576 + base), zb1 = *(const f32x4*)(zab + 1048576 + base + 4);
  bf16x8 ov;
#pragma unroll
  for (int i = 0; i < 4; ++i) {
    ov[i]     = f2b(tanh_f(u * za0[i] + fg * zb0[i] + bzv));
    ov[4 + i] = f2b(tanh_f(u * za1[i] + fg * zb1[i] + bzv));
  }
  *(bf16x8*)(zout + base) = ov;
}

// ---------- host ----------
extern "C" void kernel_launch(void* const* d_in, const int* in_sizes, int n_in,
                              void* d_out, int out_size, void* d_ws, size_t ws_size,
                              hipStream_t stream) {
  const float* x    = (const float*)d_in[0];
  const float* z0   = (const float*)d_in[1];
  const float* S    = (const float*)d_in[2];
  const float* Af   = (const float*)d_in[3];
  const float* Bw   = (const float*)d_in[4];
  const float* bz   = (const float*)d_in[5];
  const float* Ca   = (const float*)d_in[6];
  const float* Cb   = (const float*)d_in[7];
  const float* bc   = (const float*)d_in[8];
  const float* Da   = (const float*)d_in[9];
  const float* Db   = (const float*)d_in[10];
  const float* bd   = (const float*)d_in[11];
  const float* Wout = (const float*)d_in[12];
  const float* bo   = (const float*)d_in[13];
  const float* W1   = (const float*)d_in[14];
  const float* b1   = (const float*)d_in[15];
  const float* W2   = (const float*)d_in[16];
  const float* b2   = (const float*)d_in[17];
  float* out = (float*)d_out;

  // workspace layout (~147 MiB)
  char* w = (char*)d_ws;
  short* Scat = (short*)w; w += (size_t)8192 * 4096 * 2;   // bf16 [S ; S^2]          67.1 MB
  short* xsh  = (short*)w; w += (size_t)4096 * 8192 * 2;   // bf16 x shifts (tmp S^T) 67.1 MB
  short* zbuf = (short*)w; w += (size_t)2 * 1048576 * 2;   // bf16 z ping-pong         4.2 MB
  float* zab  = (float*)w; w += (size_t)2 * 1048576 * 4;   // fp32 za,zb               8.4 MB
  float* gacc = (float*)w; w += 256;                       // 2 parities x 16 floats
  size_t need = (size_t)(w - (char*)d_ws);
  if (ws_size < need) {
    fprintf(stderr, "kernel_launch: WS TOO SMALL need=%zu have=%zu -- NOT LAUNCHING\n",
            need, ws_size);
    return;
  }

  short* STt = xsh;  // temp: bf16 S^T (consumed by S^2 GEMM before xsh is written)

  conv_k<<<512, 256, 0, stream>>>(z0, zbuf, 131072);            // bf16 z_0
  conv_k<<<8192, 256, 0, stream>>>(S, Scat, 2097152);           // bf16 S
  transpose_k<<<dim3(128, 128), dim3(32, 8), 0, stream>>>(S, STt);
  gemm_big<0><<<dim3(32, 32), 256, 0, stream>>>(Scat, STt, Scat + (size_t)4096 * 4096, 4096, 4096);
  gemm_big<1><<<dim3(64, 32), 256, 0, stream>>>(x, Scat, xsh, 4096, 8192);
  hipMemsetAsync(gacc, 0, 256, stream);

  for (int t = 0; t <= 64; ++t) {
    short* znxt = zbuf + (size_t)((t + 1) & 1) * 1048576;
    step_fused<<<256, 512, 0, stream>>>(zbuf, Scat, x, xsh,
                                        Ca, Cb, bc, Da, Db, bd, Af, Bw,
                                        Wout, bo, W1, b1, W2, b2,
                                        zab, gacc, out, t);
    if (t < 64)
      update_kernel<<<512, 256, 0, stream>>>(zab, gacc, bz, znxt, t);
  }
}

// Round 14
// 6174.031 us; speedup vs baseline: 1.8763x; 1.1184x over previous
//
#include <hip/hip_runtime.h>
#include <hip/hip_bf16.h>
#include <cstdio>

// ---------- types / helpers ----------
typedef __attribute__((ext_vector_type(4))) float f32x4;
typedef __attribute__((ext_vector_type(8))) short bf16x8;  // 8 bf16 raw

__device__ __forceinline__ short f2b(float f) {
  unsigned u = __builtin_bit_cast(unsigned, f);
  unsigned r = (u + 0x7FFFu + ((u >> 16) & 1u)) >> 16;  // RNE
  return (short)r;
}
__device__ __forceinline__ float b2f(short s) {
  union { unsigned u; float f; } c;
  c.u = ((unsigned)(unsigned short)s) << 16;
  return c.f;
}
__device__ __forceinline__ float sigm(float x) { return 1.f / (1.f + __expf(-x)); }
__device__ __forceinline__ float tanh_f(float x) {
  float e = __expf(2.f * x);
  return 1.f - 2.f / (e + 1.f);
}

#define GLOAD16(gp, lp) \
  __builtin_amdgcn_global_load_lds((__attribute__((address_space(1))) const void*)(gp), \
                                   (__attribute__((address_space(3))) void*)(lp), 16, 0, 0)

// Problem dims: B=8 T=64 F=8 N=4096 H=32 G=32 K1=K2=3 R1=64 R2=8

// ---------- fp32 -> bf16 convert ----------
__global__ void conv_k(const float* __restrict__ in, short* __restrict__ out, int n8) {
  int i = blockIdx.x * 256 + threadIdx.x;
  if (i >= n8) return;
  size_t base = (size_t)i * 8;
  f32x4 a = *(const f32x4*)(in + base), b = *(const f32x4*)(in + base + 4);
  bf16x8 v;
#pragma unroll
  for (int j = 0; j < 4; ++j) { v[j] = f2b(a[j]); v[4 + j] = f2b(b[j]); }
  *(bf16x8*)(out + base) = v;
}

// ---------- transpose+convert (fp32 4096x4096 -> bf16) ----------
__global__ void transpose_k(const float* __restrict__ in, short* __restrict__ out) {
  __shared__ float tile[32][33];
  int bx = blockIdx.x * 32, by = blockIdx.y * 32;
  int tx = threadIdx.x, ty = threadIdx.y;
  for (int i = ty; i < 32; i += 8)
    tile[i][tx] = in[(size_t)(by + i) * 4096 + bx + tx];
  __syncthreads();
  for (int i = ty; i < 32; i += 8)
    out[(size_t)(bx + i) * 4096 + by + tx] = f2b(tile[tx][i]);
}

// ---------- preamble GEMM (r7-proven, 471us): C[M][N] = A[M][K]*Bt[N][K]^T ----------
template <int AF32>
__global__ __launch_bounds__(256) void gemm_pre(const void* __restrict__ Av,
                                                const short* __restrict__ Bt,
                                                short* __restrict__ C,
                                                int K, int ldc) {
  __shared__ __align__(16) short As[128][72];
  __shared__ __align__(16) short Bs[128][72];
  const int tid = threadIdx.x;
  const int lane = tid & 63, wave = tid >> 6;
  const int wm = wave >> 1, wn = wave & 1;
  const size_t m0 = (size_t)blockIdx.y * 128, n0 = (size_t)blockIdx.x * 128;
  const int r16 = lane & 15, g4 = lane >> 4;

  f32x4 acc[4][4];
#pragma unroll
  for (int mi = 0; mi < 4; ++mi)
#pragma unroll
    for (int ni = 0; ni < 4; ++ni) acc[mi][ni] = (f32x4)0.f;

  for (int kt = 0; kt < K; kt += 64) {
#pragma unroll
    for (int r = 0; r < 4; ++r) {
      int idx = r * 256 + tid;
      int row = idx >> 3;
      int kin = (idx & 7) * 8;
      if (AF32) {
        const float* A = (const float*)Av;
        const float* p = &A[(m0 + row) * (size_t)K + kt + kin];
        f32x4 a = *(const f32x4*)p, b = *(const f32x4*)(p + 4);
        bf16x8 v;
#pragma unroll
        for (int j = 0; j < 4; ++j) { v[j] = f2b(a[j]); v[4 + j] = f2b(b[j]); }
        *(bf16x8*)&As[row][kin] = v;
      } else {
        const short* A = (const short*)Av;
        *(bf16x8*)&As[row][kin] = *(const bf16x8*)&A[(m0 + row) * (size_t)K + kt + kin];
      }
      *(bf16x8*)&Bs[row][kin] = *(const bf16x8*)&Bt[(n0 + row) * (size_t)K + kt + kin];
    }
    __syncthreads();
#pragma unroll
    for (int ks = 0; ks < 2; ++ks) {
      bf16x8 af[4], bfr[4];
#pragma unroll
      for (int i = 0; i < 4; ++i) {
        af[i]  = *(const bf16x8*)&As[wm * 64 + i * 16 + r16][ks * 32 + g4 * 8];
        bfr[i] = *(const bf16x8*)&Bs[wn * 64 + i * 16 + r16][ks * 32 + g4 * 8];
      }
#pragma unroll
      for (int mi = 0; mi < 4; ++mi)
#pragma unroll
        for (int ni = 0; ni < 4; ++ni)
          acc[mi][ni] = __builtin_amdgcn_mfma_f32_16x16x32_bf16(af[mi], bfr[ni], acc[mi][ni], 0, 0, 0);
    }
    __syncthreads();
  }
#pragma unroll
  for (int mi = 0; mi < 4; ++mi) {
#pragma unroll
    for (int ni = 0; ni < 4; ++ni) {
      size_t row0 = m0 + wm * 64 + mi * 16 + g4 * 4;
      size_t col  = n0 + wn * 64 + ni * 16 + r16;
#pragma unroll
      for (int r = 0; r < 4; ++r)
        C[(row0 + r) * (size_t)ldc + col] = f2b(acc[mi][ni][r]);
    }
  }
}

// ---------- K1: fused per-step gemm + out + gate, counted-vmcnt 3-buf pipeline ----------
// 256 blocks x 512 thr, 1 block/CU (143KB LDS). Block (mhalf, ntile): rows m0..m0+127,
// cols n0..n0+31. GEMM taps stay in LDS; OUT(tau=t-1) + GATE consume them; gate writes
// za/zb to global + gacc atomics. Sync to the update is the kernel boundary.
// GEMM: tiles i,i+1 prefetched; per iter: vmcnt(3) -> s_barrier -> stage(i+2) -> MFMA(i).
__global__ __launch_bounds__(512, 1) void step_fused(
    const short* __restrict__ zbuf, const short* __restrict__ Scat,
    const float* __restrict__ x, const short* __restrict__ xsh,
    const float* __restrict__ Ca, const float* __restrict__ Cb, const float* __restrict__ bc,
    const float* __restrict__ Da, const float* __restrict__ Db, const float* __restrict__ bd,
    const float* __restrict__ Af, const float* __restrict__ Bw,
    const float* __restrict__ Wout, const float* __restrict__ bout,
    const float* __restrict__ W1, const float* __restrict__ b1,
    const float* __restrict__ W2, const float* __restrict__ b2,
    float* __restrict__ zab, float* __restrict__ gacc,
    float* __restrict__ out, int t) {
  __shared__ __align__(16) char smem[143072];
  short* AbB = (short*)smem;                      // 3 x [128*64] bf16 = 49152 B
  short* BbB = (short*)(smem + 49152);            // 3 x [64*64]  bf16 = 24576 B -> 73728
  short* Cs  = (short*)smem;                      // overlay: [128][72] bf16 (18432 B)
  short* zs  = (short*)(smem + 18432);            // overlay: [128][40] bf16 (10240 B)
  float* Fu  = (float*)(smem + 73728);            // [120][32]
  float* Fd  = (float*)(smem + 89088);            // [120][32]
  float* Fb  = (float*)(smem + 104448);           // [96][32]
  float* Fa  = (float*)(smem + 116736);           // [24][32]
  float* Wc  = (float*)(smem + 119808);           // [96][32]
  float* W1L = (float*)(smem + 132096);           // [64][32]
  float* W2L = (float*)(smem + 140288);           // [64][8]
  float* bcs   = (float*)(smem + 142336);         // [32]
  float* bds   = (float*)(smem + 142464);         // [32]
  float* boutL = (float*)(smem + 142592);         // [32]
  float* b1L   = (float*)(smem + 142720);         // [64]
  float* b2L   = (float*)(smem + 142976);         // [8]
  float* red   = (float*)(smem + 143008);         // [16]

  const int tid = threadIdx.x, lane = tid & 63, w = tid >> 6;
  const int wm = w >> 1, wn = w & 1;              // 4 m-strips x 2 n-strips
  const int r16 = lane & 15, g4 = lane >> 4;
  const int lrow8 = lane >> 3;
  const int lslot = (lane & 7) ^ lrow8;
  const int swz = r16 & 7;
  const int mhalf = blockIdx.x >> 7, ntile = blockIdx.x & 127;
  const int m0 = mhalf << 7, n0 = ntile << 5;

  // ---- filters -> LDS (fp32) ----
  for (int i = tid; i < 3840; i += 512) {
    int j = i >> 5, h = i & 31; float fu, fd;
    if (j < 96) { int k = j >> 5, hh = j & 31;
      fu = Cb[(h * 3 + k) * 32 + hh]; fd = Db[(h * 3 + k) * 32 + hh]; }
    else { int jj = j - 96, k = jj >> 3, f = jj & 7;
      fu = Ca[(h * 3 + k) * 8 + f];  fd = Da[(h * 3 + k) * 8 + f]; }
    Fu[i] = fu; Fd[i] = fd;
  }
  for (int i = tid; i < 3072; i += 512) { int j = i >> 5, h = i & 31, k = j >> 5, hh = j & 31;
    Fb[i] = Bw[(h * 3 + k) * 32 + hh]; }
  for (int i = tid; i < 768;  i += 512) { int j = i >> 5, h = i & 31, k = j >> 3, f = j & 7;
    Fa[i] = Af[(h * 3 + k) * 8 + f]; }
  for (int i = tid; i < 3072; i += 512) { int j = i >> 5, g = i & 31, k = j >> 5, hh = j & 31;
    Wc[i] = Wout[(g * 3 + k) * 32 + hh]; }
  for (int i = tid; i < 2048; i += 512) { int r1 = i >> 5, g = i & 31; W1L[i] = W1[r1 * 32 + g]; }
  if (tid < 512) { int r1 = tid >> 3, r = tid & 7; W2L[tid] = W2[r * 64 + r1]; }
  if (tid < 32) { bcs[tid] = bc[tid]; bds[tid] = bd[tid]; boutL[tid] = bout[tid]; }
  if (tid < 64) b1L[tid] = b1[tid];
  if (tid < 8)  b2L[tid] = b2[tid];
  __syncthreads();

  const short* z = zbuf + (size_t)(t & 1) * 1048576;

  // ---- pipelined GEMM: taps C[128][64] = z[m0..+128] x [tap1;tap2] of this n-tile ----
  f32x4 acc[2][2];
  acc[0][0] = acc[0][1] = acc[1][0] = acc[1][1] = (f32x4)0.f;
  auto stage = [&](int bs, int kt) {               // 3 vmem ops per lane
#pragma unroll
    for (int i = 0; i < 2; ++i) {
      int chunk = w * 2 + i, row = chunk * 8 + lrow8;
      GLOAD16(&z[(size_t)(m0 + row) * 4096 + kt + lslot * 8], &AbB[bs * 8192 + chunk * 512]);
    }
    { int row = w * 8 + lrow8;
      int grow = (row < 32) ? (n0 + row) : (4064 + n0 + row);
      GLOAD16(&Scat[(size_t)grow * 4096 + kt + lslot * 8], &BbB[bs * 4096 + w * 512]); }
  };
  stage(0, 0);
  stage(1, 64);
  for (int i = 0; i < 64; ++i) {
    if (i < 63) { asm volatile("s_waitcnt vmcnt(3)" ::: "memory"); }
    else        { asm volatile("s_waitcnt vmcnt(0)" ::: "memory"); }
    __builtin_amdgcn_s_barrier();                  // all waves: tile i resident
    __builtin_amdgcn_sched_barrier(0);
    if (i + 2 < 64) stage((i + 2) % 3, (i + 2) * 64);   // buf (i+2)%3 freed at iter i-1
    const int cur = i % 3;
#pragma unroll
    for (int ks = 0; ks < 2; ++ks) {
      const int so = ((ks * 4 + g4) ^ swz) * 8;
      bf16x8 af[2], bb[2];
#pragma unroll
      for (int ii = 0; ii < 2; ++ii) {
        af[ii] = *(const bf16x8*)&AbB[cur * 8192 + (wm * 32 + ii * 16 + r16) * 64 + so];
        bb[ii] = *(const bf16x8*)&BbB[cur * 4096 + (wn * 32 + ii * 16 + r16) * 64 + so];
      }
#pragma unroll
      for (int mi = 0; mi < 2; ++mi)
#pragma unroll
        for (int ni = 0; ni < 2; ++ni)
          acc[mi][ni] = __builtin_amdgcn_mfma_f32_16x16x32_bf16(af[mi], bb[ni], acc[mi][ni], 0, 0, 0);
    }
  }
  __syncthreads();                                 // drain before overlaying bufs with Cs/zs

  // ---- C -> Cs (stride 72), z-tile -> zs (stride 40) ----
#pragma unroll
  for (int mi = 0; mi < 2; ++mi)
#pragma unroll
    for (int ni = 0; ni < 2; ++ni) {
      int row0 = wm * 32 + mi * 16 + g4 * 4, col = wn * 32 + ni * 16 + r16;
#pragma unroll
      for (int rr = 0; rr < 4; ++rr)
        Cs[(row0 + rr) * 72 + col] = f2b(acc[mi][ni][rr]);
    }
  { int row = tid >> 2, c0 = (tid & 3) * 8;
    *(bf16x8*)&zs[row * 40 + c0] = *(const bf16x8*)&z[(size_t)(m0 + row) * 4096 + n0 + c0]; }
  __syncthreads();

  // ---- OUT phase (tau = t-1), threads 0..127 ----
  if (t >= 1 && tid < 128) {
    int b_loc = tid >> 5, nn = tid & 31;
    int b_glob = (mhalf << 2) + b_loc;
    f32x4 oa[8];
#pragma unroll
    for (int q = 0; q < 8; ++q) oa[q] = (f32x4)0.f;
    for (int j = 0; j < 96; ++j) {
      int k = j >> 5, hh = j & 31;
      float v = (k == 0) ? b2f(zs[(b_loc * 32 + hh) * 40 + nn])
                         : b2f(Cs[(b_loc * 32 + hh) * 72 + (k - 1) * 32 + nn]);
#pragma unroll
      for (int q = 0; q < 8; ++q) oa[q] += (*(const f32x4*)&Wc[j * 32 + q * 4]) * v;
    }
    f32x4 y[8];
#pragma unroll
    for (int q = 0; q < 8; ++q)
#pragma unroll
      for (int c = 0; c < 4; ++c) y[q][c] = tanh_f(oa[q][c] + boutL[q * 4 + c]);
    f32x4 o0 = { b2L[0], b2L[1], b2L[2], b2L[3] };
    f32x4 o1 = { b2L[4], b2L[5], b2L[6], b2L[7] };
    for (int r1 = 0; r1 < 64; ++r1) {
      f32x4 p = y[0] * (*(const f32x4*)&W1L[r1 * 32]);
#pragma unroll
      for (int q = 1; q < 8; ++q) p += y[q] * (*(const f32x4*)&W1L[r1 * 32 + q * 4]);
      float hv = b1L[r1] + p[0] + p[1] + p[2] + p[3];
      hv = fmaxf(hv, 0.f);
      o0 += (*(const f32x4*)&W2L[r1 * 8]) * hv;
      o1 += (*(const f32x4*)&W2L[r1 * 8 + 4]) * hv;
    }
    size_t obase = ((size_t)(b_glob * 64 + (t - 1)) * 8) * 4096 + n0 + nn;
#pragma unroll
    for (int rr = 0; rr < 4; ++rr) {
      out[obase + (size_t)rr * 4096]       = o0[rr];
      out[obase + (size_t)(4 + rr) * 4096] = o1[rr];
    }
  }

  // ---- GATE phase: za/zb -> global, gu/gd -> gacc atomics ----
  if (t < 64) {
    int nn = tid & 31; int q = tid >> 5; int b_loc = q >> 2; int h0 = (q & 3) * 8;
    int b_glob = (mhalf << 2) + b_loc;
    int n = n0 + nn;
    f32x4 zaA = (f32x4)0.f, zaB = (f32x4)0.f, zbA = (f32x4)0.f, zbB = (f32x4)0.f;
    f32x4 guA = *(const f32x4*)&bcs[h0], guB = *(const f32x4*)&bcs[h0 + 4];
    f32x4 gdA = *(const f32x4*)&bds[h0], gdB = *(const f32x4*)&bds[h0 + 4];
    for (int j = 0; j < 96; ++j) {
      int k = j >> 5, hh = j & 31;
      float v = (k == 0) ? b2f(zs[(b_loc * 32 + hh) * 40 + nn])
                         : b2f(Cs[(b_loc * 32 + hh) * 72 + (k - 1) * 32 + nn]);
      guA += (*(const f32x4*)&Fu[j * 32 + h0]) * v;  guB += (*(const f32x4*)&Fu[j * 32 + h0 + 4]) * v;
      gdA += (*(const f32x4*)&Fd[j * 32 + h0]) * v;  gdB += (*(const f32x4*)&Fd[j * 32 + h0 + 4]) * v;
      zbA += (*(const f32x4*)&Fb[j * 32 + h0]) * v;  zbB += (*(const f32x4*)&Fb[j * 32 + h0 + 4]) * v;
    }
    size_t xr = ((size_t)b_glob * 64 + t) * 8;
    for (int j = 0; j < 24; ++j) {
      int k = j >> 3, f = j & 7;
      float v = (k == 0) ? x[(xr + f) * 4096 + n]
                         : b2f(xsh[(xr + f) * 8192 + (size_t)(k - 1) * 4096 + n]);
      guA += (*(const f32x4*)&Fu[(96 + j) * 32 + h0]) * v;  guB += (*(const f32x4*)&Fu[(96 + j) * 32 + h0 + 4]) * v;
      gdA += (*(const f32x4*)&Fd[(96 + j) * 32 + h0]) * v;  gdB += (*(const f32x4*)&Fd[(96 + j) * 32 + h0 + 4]) * v;
      zaA += (*(const f32x4*)&Fa[j * 32 + h0]) * v;         zaB += (*(const f32x4*)&Fa[j * 32 + h0 + 4]) * v;
    }
    float su = 0.f, sd = 0.f;
    size_t zr = (size_t)(b_glob * 32 + h0) * 4096 + n;
#pragma unroll
    for (int i = 0; i < 4; ++i) {
      su += sigm(guA[i]) + sigm(guB[i]);
      sd += sigm(gdA[i]) + sigm(gdB[i]);
      zab[zr + (size_t)i * 4096]                 = zaA[i];
      zab[zr + (size_t)(4 + i) * 4096]           = zaB[i];
      zab[1048576 + zr + (size_t)i * 4096]       = zbA[i];
      zab[1048576 + zr + (size_t)(4 + i) * 4096] = zbB[i];
    }
#pragma unroll
    for (int off = 32; off; off >>= 1) { su += __shfl_down(su, off); sd += __shfl_down(sd, off); }
    if (lane == 0) { red[w * 2] = su; red[w * 2 + 1] = sd; }
    __syncthreads();
    if (tid < 4) {     // batch tid: waves 2*tid, 2*tid+1
      int par = t & 1, bg = (mhalf << 2) + tid;
      atomicAdd(&gacc[par * 16 + bg],     red[4 * tid] + red[4 * tid + 2]);
      atomicAdd(&gacc[par * 16 + 8 + bg], red[4 * tid + 1] + red[4 * tid + 3]);
    }
  }
}

// ---------- K2: per-step state update (bf16 z out) + zero next parity gacc ----------
__global__ __launch_bounds__(256) void update_kernel(
    const float* __restrict__ zab, float* __restrict__ gacc,
    const float* __restrict__ bz, short* __restrict__ zout, int t) {
  const int par = t & 1;
  if (blockIdx.x == 0 && threadIdx.x < 16) gacc[(par ^ 1) * 16 + threadIdx.x] = 0.f;
  size_t idx = (size_t)blockIdx.x * 256 + threadIdx.x;   // 131072 threads
  size_t base = idx * 8;
  int row = (int)(base >> 12);
  int b = row >> 5, h = row & 31;
  float u  = gacc[par * 16 + b]     * (1.f / 131072.f);
  float fg = gacc[par * 16 + 8 + b] * (1.f / 131072.f);
  float bzv = bz[h];
  f32x4 za0 = *(const f32x4*)(zab + base),           za1 = *(const f32x4*)(zab + base + 4);
  f32x4 zb0 = *(const f32x4*)(zab + 1048576 + base), zb1 = *(const f32x4*)(zab + 1048576 + base + 4);
  bf16x8 ov;
#pragma unroll
  for (int i = 0; i < 4; ++i) {
    ov[i]     = f2b(tanh_f(u * za0[i] + fg * zb0[i] + bzv));
    ov[4 + i] = f2b(tanh_f(u * za1[i] + fg * zb1[i] + bzv));
  }
  *(bf16x8*)(zout + base) = ov;
}

// ---------- host ----------
extern "C" void kernel_launch(void* const* d_in, const int* in_sizes, int n_in,
                              void* d_out, int out_size, void* d_ws, size_t ws_size,
                              hipStream_t stream) {
  const float* x    = (const float*)d_in[0];
  const float* z0   = (const float*)d_in[1];
  const float* S    = (const float*)d_in[2];
  const float* Af   = (const float*)d_in[3];
  const float* Bw   = (const float*)d_in[4];
  const float* bz   = (const float*)d_in[5];
  const float* Ca   = (const float*)d_in[6];
  const float* Cb   = (const float*)d_in[7];
  const float* bc   = (const float*)d_in[8];
  const float* Da   = (const float*)d_in[9];
  const float* Db   = (const float*)d_in[10];
  const float* bd   = (const float*)d_in[11];
  const float* Wout = (const float*)d_in[12];
  const float* bo   = (const float*)d_in[13];
  const float* W1   = (const float*)d_in[14];
  const float* b1   = (const float*)d_in[15];
  const float* W2   = (const float*)d_in[16];
  const float* b2   = (const float*)d_in[17];
  float* out = (float*)d_out;

  // workspace layout (~147 MiB)
  char* w = (char*)d_ws;
  short* Scat = (short*)w; w += (size_t)8192 * 4096 * 2;   // bf16 [S ; S^2]          67.1 MB
  short* xsh  = (short*)w; w += (size_t)4096 * 8192 * 2;   // bf16 x shifts (tmp S^T) 67.1 MB
  short* zbuf = (short*)w; w += (size_t)2 * 1048576 * 2;   // bf16 z ping-pong         4.2 MB
  float* zab  = (float*)w; w += (size_t)2 * 1048576 * 4;   // fp32 za,zb               8.4 MB
  float* gacc = (float*)w; w += 256;                       // 2 parities x 16 floats
  size_t need = (size_t)(w - (char*)d_ws);
  if (ws_size < need) {
    fprintf(stderr, "kernel_launch: WS TOO SMALL need=%zu have=%zu -- NOT LAUNCHING\n",
            need, ws_size);
    return;
  }

  short* STt = xsh;  // temp: bf16 S^T (consumed by S^2 GEMM before xsh is written)

  conv_k<<<512, 256, 0, stream>>>(z0, zbuf, 131072);            // bf16 z_0
  conv_k<<<8192, 256, 0, stream>>>(S, Scat, 2097152);           // bf16 S
  transpose_k<<<dim3(128, 128), dim3(32, 8), 0, stream>>>(S, STt);
  gemm_pre<0><<<dim3(32, 32), 256, 0, stream>>>(Scat, STt, Scat + (size_t)4096 * 4096, 4096, 4096);
  gemm_pre<1><<<dim3(64, 32), 256, 0, stream>>>(x, Scat, xsh, 4096, 8192);
  hipMemsetAsync(gacc, 0, 256, stream);

  for (int t = 0; t <= 64; ++t) {
    short* znxt = zbuf + (size_t)((t + 1) & 1) * 1048576;
    step_fused<<<256, 512, 0, stream>>>(zbuf, Scat, x, xsh,
                                        Ca, Cb, bc, Da, Db, bd, Af, Bw,
                                        Wout, bo, W1, b1, W2, b2,
                                        zab, gacc, out, t);
    if (t < 64)
      update_kernel<<<512, 256, 0, stream>>>(zab, gacc, bz, znxt, t);
  }
}